// Round 10
// baseline (16504.715 us; speedup 1.0000x reference)
//
#include <hip/hip_runtime.h>
#include <cstddef>

using bf16x8 = __attribute__((ext_vector_type(8))) short;
using f32x4  = __attribute__((ext_vector_type(4))) float;

constexpr int Bb = 128;
constexpr int Tt = 256;
constexpr int Hh = 1024;
constexpr int Oo = 64;
constexpr int NBLK = 132;         // 528 waves: 256 h1 | 256 h2 | 16 out
constexpr int FLAG_STRIDE = 32;   // dwords -> 128B between flags

__device__ __forceinline__ float bf2f(short s) {
  unsigned int u = ((unsigned int)(unsigned short)s) << 16;
  float f;
  __builtin_memcpy(&f, &u, 4);
  return f;
}
__device__ __forceinline__ short f2bf(float f) {
  unsigned int u;
  __builtin_memcpy(&u, &f, 4);
  u += 0x7fffu + ((u >> 16) & 1u);  // round-to-nearest-even
  return (short)(u >> 16);
}
__device__ __forceinline__ bf16x8 as_bf(int4 v) {
  union { int4 i; bf16x8 b; } u; u.i = v; return u.b;
}

// Agent-scope relaxed (sc1: bypass per-XCD L2, coherent at LLC) state access.
__device__ __forceinline__ unsigned ldu(const unsigned* p) {
  return __hip_atomic_load((unsigned*)p, __ATOMIC_RELAXED, __HIP_MEMORY_SCOPE_AGENT);
}
// 16B of bf16 state as 2 coherent 64-bit loads
__device__ __forceinline__ int4 ld_sc16(const short* p) {
  const unsigned long long* w = (const unsigned long long*)p;
  unsigned long long lo = __hip_atomic_load((unsigned long long*)(w + 0), __ATOMIC_RELAXED, __HIP_MEMORY_SCOPE_AGENT);
  unsigned long long hi = __hip_atomic_load((unsigned long long*)(w + 1), __ATOMIC_RELAXED, __HIP_MEMORY_SCOPE_AGENT);
  int4 v;
  v.x = (int)(lo & 0xffffffffu); v.y = (int)(lo >> 32);
  v.z = (int)(hi & 0xffffffffu); v.w = (int)(hi >> 32);
  return v;
}

// Hierarchical RMW-free grid barrier (identical to round 9):
// arrival = parallel per-block flag stores; block0 wave0 aggregates the 256
// padded flags and publishes one go word; everyone else polls only go.
__device__ __forceinline__ void grid_barrier(unsigned* flags, unsigned* go,
                                             unsigned gen, int bid, int tid) {
  __builtin_amdgcn_s_waitcnt(0);   // drain this wave's sc1 state stores to LLC
  __syncthreads();
  if (tid == 0)
    __hip_atomic_store(flags + (size_t)bid * FLAG_STRIDE, gen,
                       __ATOMIC_RELAXED, __HIP_MEMORY_SCOPE_AGENT);
  if (bid == 0) {
    if (tid < 64) {
      const unsigned* f = flags + (size_t)tid * FLAG_STRIDE;
      for (;;) {
        const unsigned a = ldu(f);
        const unsigned b = ldu(f +  64 * FLAG_STRIDE);
        const unsigned c = ldu(f + 128 * FLAG_STRIDE);
        const unsigned d = ldu(f + 192 * FLAG_STRIDE);
        if (__all((a >= gen) && (b >= gen) && (c >= gen) && (d >= gen))) break;
        __builtin_amdgcn_s_sleep(2);
      }
      if (tid == 0)
        __hip_atomic_store(go, gen, __ATOMIC_RELAXED, __HIP_MEMORY_SCOPE_AGENT);
    }
  } else if (tid < 64) {
    while (ldu(go) < gen)
      __builtin_amdgcn_s_sleep(2);
  }
  __syncthreads();
  asm volatile("" ::: "memory");
}

// Per-wave GEMM, 16x32 output tile, K=1024, no LDS/no __syncthreads.
// A (state): coherent 64-bit loads from LLC. B (weights): plain cached loads.
// 8-deep register pipeline. Accumulates into caller's acc.
__device__ __forceinline__ void wave_gemm16(
    const short* __restrict__ A, int mb, int lm, int q,
    const short* __restrict__ Bw, int bstride, int nb,
    f32x4 (&acc)[2]) {
  const short* ap  = A  + (size_t)(mb + lm) * Hh + q * 8;
  const short* bp0 = Bw + (size_t)(nb + lm) * bstride + q * 8;
  const short* bp1 = bp0 + (size_t)16 * bstride;
  int4 av[8], b0v[8], b1v[8];
#pragma unroll
  for (int c = 0; c < 8; ++c) {
    av[c]  = ld_sc16(ap + c * 32);
    b0v[c] = *(const int4*)(bp0 + c * 32);
    b1v[c] = *(const int4*)(bp1 + c * 32);
  }
#pragma unroll
  for (int c = 0; c < 32; ++c) {
    const int s = c & 7;
    const bf16x8 a  = as_bf(av[s]);
    const bf16x8 b0 = as_bf(b0v[s]);
    const bf16x8 b1 = as_bf(b1v[s]);
    if (c + 8 < 32) {
      av[s]  = ld_sc16(ap + (c + 8) * 32);
      b0v[s] = *(const int4*)(bp0 + (c + 8) * 32);
      b1v[s] = *(const int4*)(bp1 + (c + 8) * 32);
    }
    acc[0] = __builtin_amdgcn_mfma_f32_16x16x32_bf16(a, b0, acc[0], 0, 0, 0);
    acc[1] = __builtin_amdgcn_mfma_f32_16x16x32_bf16(a, b1, acc[1], 0, 0, 0);
  }
}

// C/D layout (verified m89/m91): col = lane&15, row = (lane>>4)*4 + reg
#define TL(MB, NB, ACC, ...) do {                                          \
    _Pragma("unroll")                                                      \
    for (int n = 0; n < 2; ++n) {                                          \
      _Pragma("unroll")                                                    \
      for (int r = 0; r < 4; ++r) {                                        \
        const int row = (MB) + q * 4 + r;                                  \
        const int col = (NB) + n * 16 + lm;                                \
        const float z = (ACC)[n][r];                                       \
        __VA_ARGS__;                                                       \
      } } } while (0)

// pack bf16 pair across lane (lm, lm^1), store one coherent dword from even lm
#define ST_BF16_PAIR(BASE, ROW, COL, HV) do {                              \
    const int _ov = __shfl_xor((int)(unsigned short)(HV), 1, 64);          \
    if ((lm & 1) == 0) {                                                   \
      const unsigned _pk = (unsigned)(unsigned short)(HV) | ((unsigned)_ov << 16); \
      __hip_atomic_store((unsigned*)((BASE) + (ROW) * Hh + (COL)), _pk,    \
                         __ATOMIC_RELAXED, __HIP_MEMORY_SCOPE_AGENT);      \
    } } while (0)

#define SET_ACC(ACC, V0, V1) do {                                          \
    (ACC)[0] = (f32x4){(V0), (V0), (V0), (V0)};                            \
    (ACC)[1] = (f32x4){(V1), (V1), (V1), (V1)};                            \
  } while (0)

struct RP {
  short* h1bf;    // ring of 4: h1(t) at slot t&3   [4][128][1024] bf16, sc1
  short* h2bf;    // ring of 2: h2(t) at slot t&1   [2][128][1024] bf16, sc1
  float* h2f;     // fp32 master of h2(t-1), wave-local plain RW
  const short* prex;
  const short* whh1; const short* wih2; const short* whh2;
  const short* wg; const short* wo1; const short* wo2;
  const float* b_ih2; const float* b_hh2;
  const float* bg; const float* bo1; const float* bo2;
  float* out;
  unsigned* flags;
  unsigned* go;
};

// Software-pipelined schedule, ONE barrier per phase, 258 phases:
//  phase k: h1-waves (gw<256)  compute h1(k-1)  [k in 1..Tt]
//           h2-waves (gw<512)  compute h2(k-2)  [k in 2..Tt+1]
//             = 4 GEMMs (Wih2/Whh2/Wg1/Wg2) + local u/blend (no intermediates)
//           out-waves (gw<528) compute out(k-3) [k in 3..Tt+2], both heads
__global__ void __launch_bounds__(256, 1) rnn_kernel(RP p) {
  const int tid = threadIdx.x;
  const int lane = tid & 63;
  const int wv = tid >> 6;
  const int lm = lane & 15;
  const int q = lane >> 4;
  const int bid = blockIdx.x;
  const int gw = bid * 4 + wv;

  int role, g;
  if      (gw < 256) { role = 0; g = gw; }
  else if (gw < 512) { role = 1; g = gw - 256; }
  else               { role = 2; g = gw - 512; }
  const int mb = (role == 2) ? (g >> 1) * 16 : (g >> 5) * 16;
  const int nb = (role == 2) ? (g & 1) * 32  : (g & 31) * 32;

  // biases (register-resident)
  float bh2_0 = 0.f, bh2_1 = 0.f, bu_0 = 0.f, bu_1 = 0.f;
  float bo1_0 = 0.f, bo1_1 = 0.f, bo2_0 = 0.f, bo2_1 = 0.f;
  {
    const int c0 = nb + lm, c1 = nb + 16 + lm;
    if (role == 1) {
      bh2_0 = p.b_ih2[c0] + p.b_hh2[c0]; bh2_1 = p.b_ih2[c1] + p.b_hh2[c1];
      bu_0  = p.bg[c0];                  bu_1  = p.bg[c1];
    } else if (role == 2) {
      bo1_0 = p.bo1[c0]; bo1_1 = p.bo1[c1];
      bo2_0 = p.bo2[c0]; bo2_1 = p.bo2[c1];
    }
  }
  const size_t HS = (size_t)Bb * Hh;   // one ring slot

  unsigned gen = 0;
  for (int k = 1; k <= Tt + 2; ++k) {
    if (role == 0) {
      if (k <= Tt) {
        const int t = k - 1;
        // prefetch prex (plain cached; streamed once)
        short prs[2][4];
        const short* pr = p.prex + (size_t)t * HS;
#pragma unroll
        for (int n = 0; n < 2; ++n)
#pragma unroll
          for (int r = 0; r < 4; ++r)
            prs[n][r] = pr[(size_t)(mb + q * 4 + r) * Hh + nb + n * 16 + lm];
        f32x4 acc[2];
        SET_ACC(acc, 0.f, 0.f);
        wave_gemm16(p.h1bf + ((k + 2) & 3) * HS, mb, lm, q, p.whh1, Hh, nb, acc);  // h1(k-2)
        short* h1o = p.h1bf + ((k + 3) & 3) * HS;                                  // slot (k-1)&3
        TL(mb, nb, acc, {
          const short hv = f2bf(tanhf(z + bf2f(prs[n][r])));
          ST_BF16_PAIR(h1o, row, col, hv);
        });
      }
    } else if (role == 1) {
      if (k >= 2 && k <= Tt + 1) {
        const int t = k - 2;
        const short* h2prev = p.h2bf + ((k + 1) & 1) * HS;   // h2(t-1) = slot (k-3)&1
        f32x4 acch[2];
        SET_ACC(acch, bh2_0, bh2_1);
        wave_gemm16(p.h1bf + ((k + 2) & 3) * HS, mb, lm, q, p.wih2, Hh, nb, acch); // h1(t)=h1(k-2)
        if (t > 0) {
          wave_gemm16(h2prev, mb, lm, q, p.whh2, Hh, nb, acch);
          f32x4 accu[2];
          SET_ACC(accu, bu_0, bu_1);
          wave_gemm16(p.h1bf + ((k + 1) & 3) * HS, mb, lm, q, p.wg, 2 * Hh, nb, accu);      // h1(t-1)
          wave_gemm16(h2prev, mb, lm, q, p.wg + Hh, 2 * Hh, nb, accu);                      // h2(t-1)
          short* h2o = p.h2bf + (k & 1) * HS;                // slot t&1
          TL(mb, nb, acch, {
            const int idx = row * Hh + col;
            const float u   = 1.0f / (1.0f + expf(-accu[n][r]));
            const float h2o_ = p.h2f[idx];                   // wave-local fp32 master
            const float hn  = tanhf(z);
            const float nv  = fmaf(u, hn - h2o_, h2o_);
            p.h2f[idx] = nv;
            const short hv = f2bf(nv);
            ST_BF16_PAIR(h2o, row, col, hv);
          });
        } else {
          // t==0: u=1 -> h2(0) = tanh(acc_h2)  (h2(-1)=0 contributes nothing)
          short* h2o = p.h2bf + (k & 1) * HS;
          TL(mb, nb, acch, {
            const int idx = row * Hh + col;
            const float nv = tanhf(z);
            p.h2f[idx] = nv;
            const short hv = f2bf(nv);
            ST_BF16_PAIR(h2o, row, col, hv);
          });
        }
      }
    } else {
      if (k >= 3) {
        const int t = k - 3;
        f32x4 acc1[2], acc2[2];
        SET_ACC(acc1, bo1_0, bo1_1);
        wave_gemm16(p.h1bf + ((k + 1) & 3) * HS, mb, lm, q, p.wo1, Hh, nb, acc1);  // h1(t)=h1(k-3)
        SET_ACC(acc2, bo2_0, bo2_1);
        wave_gemm16(p.h2bf + ((k + 1) & 1) * HS, mb, lm, q, p.wo2, Hh, nb, acc2);  // h2(t)=h2(k-3)
        TL(mb, nb, acc1, {
          p.out[(size_t)row * (Tt * Oo) + (size_t)t * Oo + col] =
              tanhf(z) + tanhf(acc2[n][r]);
        });
      }
    }
    if (k < Tt + 2) {
      ++gen;
      grid_barrier(p.flags, p.go, gen, bid, tid);
    }
  }
}

// pre_x[t][b][j] = x[b,t,:] @ W_ih1[j,:] + b_ih1[j] + b_hh1[j]  (stored bf16)
__global__ void __launch_bounds__(256) prex_kernel(
    const float* __restrict__ x, const float* __restrict__ wih1,
    const float* __restrict__ b_ih1, const float* __restrict__ b_hh1,
    short* __restrict__ prex) {
  const int tid = threadIdx.x;
  const int lane = tid & 63;
  const int wv = tid >> 6;
  const int lm = lane & 15;
  const int q = lane >> 4;
  const int bm = blockIdx.x >> 4;
  const int bn = blockIdx.x & 15;
  const int rowbase = bm * 64;
  const int col = bn * 64 + wv * 16 + lm;

  const f32x4 z4 = {0.f, 0.f, 0.f, 0.f};
  f32x4 acc[4];
#pragma unroll
  for (int mt = 0; mt < 4; ++mt) acc[mt] = z4;

#pragma unroll
  for (int kc = 0; kc < 2; ++kc) {
    const float* bp = wih1 + col * 64 + kc * 32 + q * 8;
    bf16x8 bf;
#pragma unroll
    for (int j = 0; j < 8; ++j) bf[j] = f2bf(bp[j]);
#pragma unroll
    for (int mt = 0; mt < 4; ++mt) {
      const float* ap = x + (size_t)(rowbase + mt * 16 + lm) * 64 + kc * 32 + q * 8;
      bf16x8 af;
#pragma unroll
      for (int j = 0; j < 8; ++j) af[j] = f2bf(ap[j]);
      acc[mt] = __builtin_amdgcn_mfma_f32_16x16x32_bf16(af, bf, acc[mt], 0, 0, 0);
    }
  }
  const float bia = b_ih1[col] + b_hh1[col];
#pragma unroll
  for (int mt = 0; mt < 4; ++mt) {
#pragma unroll
    for (int r = 0; r < 4; ++r) {
      const int row = rowbase + mt * 16 + q * 4 + r;  // row = b*256 + t
      const int b  = row >> 8;
      const int tt = row & 255;
      prex[((size_t)tt * Bb + b) * Hh + col] = f2bf(acc[mt][r] + bia);
    }
  }
}

__global__ void conv_kernel(const float* __restrict__ s, short* __restrict__ d, int n) {
  int i = blockIdx.x * blockDim.x + threadIdx.x;
  const int stride = gridDim.x * blockDim.x;
  for (; i < n; i += stride) d[i] = f2bf(s[i]);
}

__global__ void init_kernel(short* h1bf, short* h2bf, float* h2f,
                            unsigned* flags, unsigned* go) {
  const int i = blockIdx.x * blockDim.x + threadIdx.x;  // exactly 128*1024
  h1bf[3 * Bb * Hh + i] = 0;   // h1(-1) ring slot 3
  h2bf[1 * Bb * Hh + i] = 0;   // h2(-1) ring slot 1
  h2f[i] = 0.f;
  if (i < 256) flags[i * FLAG_STRIDE] = (i < NBLK) ? 0u : 0xFFFFFFFFu;
  if (i == 0) *go = 0u;
}

extern "C" void kernel_launch(void* const* d_in, const int* in_sizes, int n_in,
                              void* d_out, int out_size, void* d_ws, size_t ws_size,
                              hipStream_t stream) {
  (void)in_sizes; (void)n_in; (void)out_size; (void)ws_size;
  const float* x      = (const float*)d_in[0];
  const float* W_ih1  = (const float*)d_in[1];
  const float* b_ih1  = (const float*)d_in[2];
  const float* W_hh1  = (const float*)d_in[3];
  const float* b_hh1  = (const float*)d_in[4];
  const float* W_ih2  = (const float*)d_in[5];
  const float* b_ih2  = (const float*)d_in[6];
  const float* W_hh2  = (const float*)d_in[7];
  const float* b_hh2  = (const float*)d_in[8];
  const float* Wg     = (const float*)d_in[9];
  const float* bg     = (const float*)d_in[10];
  const float* Wo1    = (const float*)d_in[11];
  const float* bo1    = (const float*)d_in[12];
  const float* Wo2    = (const float*)d_in[13];
  const float* bo2    = (const float*)d_in[14];

  char* ws = (char*)d_ws;
  size_t off = 0;
  auto alloc = [&](size_t bytes) -> void* {
    void* ptr = ws + off;
    off += (bytes + 255) & ~(size_t)255;
    return ptr;
  };
  short* whh1 = (short*)alloc((size_t)Hh * Hh * 2);
  short* wih2 = (short*)alloc((size_t)Hh * Hh * 2);
  short* whh2 = (short*)alloc((size_t)Hh * Hh * 2);
  short* wg   = (short*)alloc((size_t)Hh * 2 * Hh * 2);
  short* wo1  = (short*)alloc((size_t)Oo * Hh * 2);
  short* wo2  = (short*)alloc((size_t)Oo * Hh * 2);
  short* prex = (short*)alloc((size_t)Bb * Tt * Hh * 2);
  short* h1bf = (short*)alloc((size_t)4 * Bb * Hh * 2);
  short* h2bf = (short*)alloc((size_t)2 * Bb * Hh * 2);
  float* h2f  = (float*)alloc((size_t)Bb * Hh * 4);
  unsigned* flags = (unsigned*)alloc(256 * FLAG_STRIDE * 4);   // 32 KB
  unsigned* go    = (unsigned*)alloc(256);

  conv_kernel<<<1024, 256, 0, stream>>>(W_hh1, whh1, Hh * Hh);
  conv_kernel<<<1024, 256, 0, stream>>>(W_ih2, wih2, Hh * Hh);
  conv_kernel<<<1024, 256, 0, stream>>>(W_hh2, whh2, Hh * Hh);
  conv_kernel<<<2048, 256, 0, stream>>>(Wg,    wg,   Hh * 2 * Hh);
  conv_kernel<<<256,  256, 0, stream>>>(Wo1,   wo1,  Oo * Hh);
  conv_kernel<<<256,  256, 0, stream>>>(Wo2,   wo2,  Oo * Hh);
  init_kernel<<<512, 256, 0, stream>>>(h1bf, h2bf, h2f, flags, go);
  prex_kernel<<<8192, 256, 0, stream>>>(x, W_ih1, b_ih1, b_hh1, prex);

  RP p;
  p.h1bf = h1bf; p.h2bf = h2bf; p.h2f = h2f;
  p.prex = prex;
  p.whh1 = whh1; p.wih2 = wih2; p.whh2 = whh2;
  p.wg = wg; p.wo1 = wo1; p.wo2 = wo2;
  p.b_ih2 = b_ih2; p.b_hh2 = b_hh2;
  p.bg = bg; p.bo1 = bo1; p.bo2 = bo2;
  p.out = (float*)d_out;
  p.flags = flags;
  p.go = go;

  rnn_kernel<<<NBLK, 256, 0, stream>>>(p);
}